// Round 14
// baseline (77.474 us; speedup 1.0000x reference)
//
#include <hip/hip_runtime.h>
#include <math.h>

#define NODES 1024
#define BATCH 16
#define TLEN 24
#define LAYERS 24
#define NLANES (NODES * BATCH) /* 16384 */
#define LOG2E 1.44269504088896340736f

typedef float v2f __attribute__((ext_vector_type(2)));

#if __has_builtin(__builtin_amdgcn_rcpf)
__device__ __forceinline__ float fast_rcp(float x) { return __builtin_amdgcn_rcpf(x); }
#else
__device__ __forceinline__ float fast_rcp(float x) { return 1.0f / x; }
#endif

#if __has_builtin(__builtin_amdgcn_exp2f)
__device__ __forceinline__ float fast_exp2(float x) { return __builtin_amdgcn_exp2f(x); }
#else
__device__ __forceinline__ float fast_exp2(float x) { return exp2f(x); }
#endif

#if __has_builtin(__builtin_elementwise_fma)
__device__ __forceinline__ v2f pk_fma(v2f a, v2f b, v2f c) {
    return __builtin_elementwise_fma(a, b, c);
}
#else
__device__ __forceinline__ v2f pk_fma(v2f a, v2f b, v2f c) {
    v2f d; d.x = fmaf(a.x, b.x, c.x); d.y = fmaf(a.y, b.y, c.y); return d;
}
#endif

struct GruK2 { v2f rW, rU, rC, zW, zU, zC, nW, nC, nU, nD; };
struct GruKs { float rW, rU, rC, zW, zU, zC, nW, nC, nU, nD; };

__device__ __forceinline__ GruK2 make_k2(
    const float* __restrict__ w_ih, const float* __restrict__ w_hh,
    const float* __restrict__ b_ih, const float* __restrict__ b_hh,
    int la, int lb)
{
    GruK2 K;
    #pragma unroll
    for (int s = 0; s < 2; ++s) {
        const int l = s ? lb : la;
        K.rW[s] = -LOG2E * w_ih[l*3+0]; K.rU[s] = -LOG2E * w_hh[l*3+0];
        K.rC[s] = -LOG2E * (b_ih[l*3+0] + b_hh[l*3+0]);
        K.zW[s] = -LOG2E * w_ih[l*3+1]; K.zU[s] = -LOG2E * w_hh[l*3+1];
        K.zC[s] = -LOG2E * (b_ih[l*3+1] + b_hh[l*3+1]);
        K.nW[s] = -2.0f*LOG2E * w_ih[l*3+2]; K.nC[s] = -2.0f*LOG2E * b_ih[l*3+2];
        K.nU[s] = -2.0f*LOG2E * w_hh[l*3+2]; K.nD[s] = -2.0f*LOG2E * b_hh[l*3+2];
    }
    return K;
}

__device__ __forceinline__ GruKs make_ks(
    const float* __restrict__ w_ih, const float* __restrict__ w_hh,
    const float* __restrict__ b_ih, const float* __restrict__ b_hh, int l)
{
    GruKs K;
    K.rW = -LOG2E * w_ih[l*3+0]; K.rU = -LOG2E * w_hh[l*3+0];
    K.rC = -LOG2E * (b_ih[l*3+0] + b_hh[l*3+0]);
    K.zW = -LOG2E * w_ih[l*3+1]; K.zU = -LOG2E * w_hh[l*3+1];
    K.zC = -LOG2E * (b_ih[l*3+1] + b_hh[l*3+1]);
    K.nW = -2.0f*LOG2E * w_ih[l*3+2]; K.nC = -2.0f*LOG2E * b_ih[l*3+2];
    K.nU = -2.0f*LOG2E * w_hh[l*3+2]; K.nD = -2.0f*LOG2E * b_hh[l*3+2];
    return K;
}

// Tick split into two halves (phase A+B / C+D+E). Per-component arithmetic
// bit-identical to rounds 4-13: er/ez/en are e^{-a} forms; r = 1/(1+er);
// h' = (ez*(1-en) + h*(1+en)) / ((1+ez)*(1+en)).
struct TickSt { v2f er01, ez01, in01; float er2, ez2, in2; };

// Part 1 — phases A (gate args) + B (6x exp2). `xa` is the layer-L0 input
// (rel in steady; original input on the lead lane during fill).
__device__ __forceinline__ TickSt part1(const GruK2& K01, const GruKs& K2,
                                        v2f h01, float h2, float xa)
{
    TickSt S;
    S.in01.x = xa; S.in01.y = h01.x;
    S.in2 = h01.y;
    float ar2 = fmaf(K2.rU, h2, fmaf(K2.rW, S.in2, K2.rC));
    float az2 = fmaf(K2.zU, h2, fmaf(K2.zW, S.in2, K2.zC));
    v2f ar01 = pk_fma(K01.rU, h01, pk_fma(K01.rW, S.in01, K01.rC));
    v2f az01 = pk_fma(K01.zU, h01, pk_fma(K01.zW, S.in01, K01.zC));
    S.er2 = fast_exp2(ar2);
    S.ez2 = fast_exp2(az2);
    S.er01.x = fast_exp2(ar01.x); S.er01.y = fast_exp2(ar01.y);
    S.ez01.x = fast_exp2(az01.x); S.ez01.y = fast_exp2(az01.y);
    return S;
}

// Part 2 — phases C (r-rcp) + D (n-args + exp2) + E (finals). Updates h in
// place; h2 finishes first so the caller's shfl can issue under h01's tail.
__device__ __forceinline__ void part2(const GruK2& K01, const GruKs& K2,
                                      const TickSt& S, v2f& h01, float& h2)
{
    const v2f ONE = (v2f){1.0f, 1.0f};
    float r2 = fast_rcp(1.0f + S.er2);
    v2f e1 = S.er01 + ONE;
    v2f r01; r01.x = fast_rcp(e1.x); r01.y = fast_rcp(e1.y);
    float an2 = fmaf(r2, fmaf(K2.nU, h2, K2.nD), fmaf(K2.nW, S.in2, K2.nC));
    v2f an01 = pk_fma(r01, pk_fma(K01.nU, h01, K01.nD), pk_fma(K01.nW, S.in01, K01.nC));
    float en2 = fast_exp2(an2);
    v2f en01; en01.x = fast_exp2(an01.x); en01.y = fast_exp2(an01.y);
    float num2 = fmaf(en2, h2 - S.ez2, h2 + S.ez2);
    float den2 = (1.0f + S.ez2) * (1.0f + en2);
    h2 = num2 * fast_rcp(den2);
    v2f num01 = pk_fma(en01, h01 - S.ez01, h01 + S.ez01);
    v2f den01 = (S.ez01 + ONE) * (en01 + ONE);
    v2f rd; rd.x = fast_rcp(den01.x); rd.y = fast_rcp(den01.y);
    h01 = num01 * rd;
}

// Ring-pipelined GRU: 8-lane rings, 3 CONSECUTIVE layers per lane, ONE chain
// per lane, SW-pipelined ring handoff (r9/r13 structure, bit-identical math).
// Round-14 change: WAVE-PARITY PHASE STAGGER. The two co-resident waves per
// SIMD run the identical loop and stall lockstep on the same trans phases
// (busy% pinned at 68% across r8-r13). Odd-parity waves run the steady loop
// rotated by half a tick ({C..E(k); A,B(k+1)} with an A,B prologue) so their
// trans bursts anti-align with even waves'. Parity = (blockIdx + wid) & 1:
// a SIMD's two waves are the same wave-slot of two adjacent blocks.
__global__ __launch_bounds__(256, 2) void gru_pipe_kernel(
    const float* __restrict__ inputs, const float* __restrict__ w_ih,
    const float* __restrict__ w_hh, const float* __restrict__ b_ih,
    const float* __restrict__ b_hh, const int* __restrict__ horizon_p,
    float* __restrict__ hv, float* __restrict__ h_out)
{
    __shared__ float xl[32][TLEN + 1];   // 32 chains/block, +1 pad
    const int tid = threadIdx.x;
    const int wid = tid >> 6;
    const int lane = tid & 63;
    const int ring = lane >> 3;          // 0..7
    const int sl = lane & 7;             // ring-local lane
    const int L0 = 3 * sl;               // first owned layer
    const int chain_local = wid * 8 + ring;
    const int c = blockIdx.x * 32 + chain_local;

    const GruK2 K01 = make_k2(w_ih, w_hh, b_ih, b_hh, L0, L0 + 1);
    const GruKs K2  = make_ks(w_ih, w_hh, b_ih, b_hh, L0 + 2);

    for (int i = tid; i < 32 * TLEN; i += 256) {
        const int cl = i / TLEN, t = i - cl * TLEN;
        const int cc = blockIdx.x * 32 + cl;
        const int node = cc >> 4, b = cc & 15;
        xl[cl][t] = inputs[((size_t)b * NODES + node) * TLEN + t];
    }
    __syncthreads();

    const int H = *horizon_p;
    const int last = H * TLEN;                        // 192 for H=8
    const int ringsrc = (lane & 56) | ((sl + 7) & 7); // prev lane in 8-ring
    const bool lead = (sl == 0);
    const float* xrow = &xl[chain_local][0];

    v2f h01 = (v2f){0.0f, 0.0f};
    float h2 = 0.0f;
    float rel = 0.0f;   // == shfl(h2 after tick k-1); h2 init 0 -> rel 0

    // Fill: ticks [0, 24). Masked candidate update via part1+part2.
    for (int k = 0; k < TLEN; ++k) {
        float inA = lead ? xrow[k] : rel;
        TickSt S = part1(K01, K2, h01, h2, inA);
        v2f th01 = h01; float th2 = h2;
        part2(K01, K2, S, th01, th2);
        h01.x = (k >= L0 + 0) ? th01.x : h01.x;
        h01.y = (k >= L0 + 1) ? th01.y : h01.y;
        h2    = (k >= L0 + 2) ? th2   : h2;
        rel = __shfl(h2, ringsrc, 64);               // for tick k+1
    }
    // Steady: ticks [24, last), no masks, parity-staggered phase order.
    if (((blockIdx.x + wid) & 1) == 0) {
        #pragma unroll 4
        for (int k = TLEN; k < last; ++k) {
            TickSt S = part1(K01, K2, h01, h2, rel);
            part2(K01, K2, S, h01, h2);
            rel = __shfl(h2, ringsrc, 64);
        }
    } else {
        // Rotated: A,B prologue; loop body = {C..E(k); shfl; A,B(k+1)}.
        TickSt S = part1(K01, K2, h01, h2, rel);
        #pragma unroll 4
        for (int k = TLEN; k < last - 1; ++k) {
            part2(K01, K2, S, h01, h2);
            rel = __shfl(h2, ringsrc, 64);
            S = part1(K01, K2, h01, h2, rel);
        }
        part2(K01, K2, S, h01, h2);
        rel = __shfl(h2, ringsrc, 64);
    }
    // Drain: ticks [last, last+23). Layer l's last update is tick l+last-1.
    for (int k = last; k < last + LAYERS - 1; ++k) {
        TickSt S = part1(K01, K2, h01, h2, rel);
        v2f th01 = h01; float th2 = h2;
        part2(K01, K2, S, th01, th2);
        h01.x = (k < L0 + 0 + last) ? th01.x : h01.x;
        h01.y = (k < L0 + 1 + last) ? th01.y : h01.y;
        h2    = (k < L0 + 2 + last) ? th2   : h2;
        rel = __shfl(h2, ringsrc, 64);
    }

    // Outputs: hv[L][c] scratch and h_out[node][L][b].
    const int node = c >> 4, b = c & 15;
    float* ho = h_out + (size_t)node * (LAYERS * BATCH) + b;
    hv[(size_t)(L0 + 0) * NLANES + c] = h01.x;  ho[(L0 + 0) * BATCH] = h01.x;
    hv[(size_t)(L0 + 1) * NLANES + c] = h01.y;  ho[(L0 + 1) * BATCH] = h01.y;
    hv[(size_t)(L0 + 2) * NLANES + c] = h2;     ho[(L0 + 2) * BATCH] = h2;
}

// adj[l][i][j] = dot_b(hv[l,i,:], hv[l,j,:]) * inv_i * inv_j.
// 64x64 tile per 256-thread block; B tile transposed in LDS (conflict-free).
// At the HBM-write floor (~100 MB output at ~6.5 TB/s measured, ~16 us).
__global__ __launch_bounds__(256) void adj_kernel(
    const float* __restrict__ hv, float* __restrict__ adj)
{
    const int l = blockIdx.z;
    const int i0 = blockIdx.y * 64;
    const int j0 = blockIdx.x * 64;
    __shared__ float As[64 * 16];   // [row][k]
    __shared__ float Bt[16 * 64];   // [k][col]
    __shared__ float iA[64];
    __shared__ float iB[64];
    const int tid = threadIdx.x;
    const float* hvl = hv + (size_t)l * NLANES;

    ((float4*)As)[tid] = ((const float4*)(hvl + (size_t)i0 * 16))[tid];
    {
        const int j = tid >> 2;
        const int kc = (tid & 3) * 4;
        float4 bv = *(const float4*)(hvl + (size_t)(j0 + j) * 16 + kc);
        Bt[(kc + 0) * 64 + j] = bv.x;
        Bt[(kc + 1) * 64 + j] = bv.y;
        Bt[(kc + 2) * 64 + j] = bv.z;
        Bt[(kc + 3) * 64 + j] = bv.w;
    }
    __syncthreads();

    if (tid < 64) {
        float s = 0.0f;
        #pragma unroll
        for (int k = 0; k < 16; ++k) { float v = As[tid * 16 + k]; s = fmaf(v, v, s); }
        iA[tid] = fast_rcp(fmaxf(sqrtf(s), 1e-8f));
    } else if (tid < 128) {
        const int j = tid - 64;
        float s = 0.0f;
        #pragma unroll
        for (int k = 0; k < 16; ++k) { float v = Bt[k * 64 + j]; s = fmaf(v, v, s); }
        iB[j] = fast_rcp(fmaxf(sqrtf(s), 1e-8f));
    }
    __syncthreads();

    const int ty = tid >> 4;   // row group (4 rows)
    const int tx = tid & 15;   // col group (4 cols = 1 float4)

    float4 acc0 = {0,0,0,0}, acc1 = {0,0,0,0}, acc2 = {0,0,0,0}, acc3 = {0,0,0,0};
    #pragma unroll
    for (int kk = 0; kk < 4; ++kk) {
        float4 a0 = ((const float4*)As)[(ty * 4 + 0) * 4 + kk];
        float4 a1 = ((const float4*)As)[(ty * 4 + 1) * 4 + kk];
        float4 a2 = ((const float4*)As)[(ty * 4 + 2) * 4 + kk];
        float4 a3 = ((const float4*)As)[(ty * 4 + 3) * 4 + kk];
        #pragma unroll
        for (int e = 0; e < 4; ++e) {
            const int k = kk * 4 + e;
            float4 bk = ((const float4*)Bt)[k * 16 + tx];
            const float a0e = (e == 0) ? a0.x : (e == 1) ? a0.y : (e == 2) ? a0.z : a0.w;
            const float a1e = (e == 0) ? a1.x : (e == 1) ? a1.y : (e == 2) ? a1.z : a1.w;
            const float a2e = (e == 0) ? a2.x : (e == 1) ? a2.y : (e == 2) ? a2.z : a2.w;
            const float a3e = (e == 0) ? a3.x : (e == 1) ? a3.y : (e == 2) ? a3.z : a3.w;
            acc0.x = fmaf(a0e, bk.x, acc0.x); acc0.y = fmaf(a0e, bk.y, acc0.y);
            acc0.z = fmaf(a0e, bk.z, acc0.z); acc0.w = fmaf(a0e, bk.w, acc0.w);
            acc1.x = fmaf(a1e, bk.x, acc1.x); acc1.y = fmaf(a1e, bk.y, acc1.y);
            acc1.z = fmaf(a1e, bk.z, acc1.z); acc1.w = fmaf(a1e, bk.w, acc1.w);
            acc2.x = fmaf(a2e, bk.x, acc2.x); acc2.y = fmaf(a2e, bk.y, acc2.y);
            acc2.z = fmaf(a2e, bk.z, acc2.z); acc2.w = fmaf(a2e, bk.w, acc2.w);
            acc3.x = fmaf(a3e, bk.x, acc3.x); acc3.y = fmaf(a3e, bk.y, acc3.y);
            acc3.z = fmaf(a3e, bk.z, acc3.z); acc3.w = fmaf(a3e, bk.w, acc3.w);
        }
    }

    float* out = adj + (size_t)l * NODES * NODES;
    const float4 ib4 = ((const float4*)iB)[tx];
    #pragma unroll
    for (int ii = 0; ii < 4; ++ii) {
        const int i = i0 + ty * 4 + ii;
        const float si = iA[ty * 4 + ii];
        float4 a = (ii == 0) ? acc0 : (ii == 1) ? acc1 : (ii == 2) ? acc2 : acc3;
        float4 w;
        w.x = a.x * si * ib4.x;
        w.y = a.y * si * ib4.y;
        w.z = a.z * si * ib4.z;
        w.w = a.w * si * ib4.w;
        *(float4*)(out + (size_t)i * NODES + j0 + tx * 4) = w;
    }
}

extern "C" void kernel_launch(void* const* d_in, const int* in_sizes, int n_in,
                              void* d_out, int out_size, void* d_ws, size_t ws_size,
                              hipStream_t stream) {
    const float* inputs = (const float*)d_in[0];
    const float* w_ih   = (const float*)d_in[1];
    const float* w_hh   = (const float*)d_in[2];
    const float* b_ih   = (const float*)d_in[3];
    const float* b_hh   = (const float*)d_in[4];
    const int*   horiz  = (const int*)d_in[5];

    float* adj   = (float*)d_out;                                   // [24,1024,1024]
    float* h_out = (float*)d_out + (size_t)LAYERS * NODES * NODES;  // [1024,24,16]
    float* hv    = (float*)d_ws;                                    // [24][16384]

    // 512 blocks x 256 threads = 2048 waves = 2/SIMD; 32 chains/block
    gru_pipe_kernel<<<NLANES / 32, 256, 0, stream>>>(inputs, w_ih, w_hh, b_ih, b_hh,
                                                     horiz, hv, h_out);

    dim3 grid(NODES / 64, NODES / 64, LAYERS);
    adj_kernel<<<grid, 256, 0, stream>>>(hv, adj);
}

// Round 15
// 76.896 us; speedup vs baseline: 1.0075x; 1.0075x over previous
//
#include <hip/hip_runtime.h>
#include <math.h>

#define NODES 1024
#define BATCH 16
#define TLEN 24
#define LAYERS 24
#define NLANES (NODES * BATCH) /* 16384 */
#define LOG2E 1.44269504088896340736f

typedef float v2f __attribute__((ext_vector_type(2)));

#if __has_builtin(__builtin_amdgcn_rcpf)
__device__ __forceinline__ float fast_rcp(float x) { return __builtin_amdgcn_rcpf(x); }
#else
__device__ __forceinline__ float fast_rcp(float x) { return 1.0f / x; }
#endif

#if __has_builtin(__builtin_amdgcn_exp2f)
__device__ __forceinline__ float fast_exp2(float x) { return __builtin_amdgcn_exp2f(x); }
#else
__device__ __forceinline__ float fast_exp2(float x) { return exp2f(x); }
#endif

#if __has_builtin(__builtin_elementwise_fma)
__device__ __forceinline__ v2f pk_fma(v2f a, v2f b, v2f c) {
    return __builtin_elementwise_fma(a, b, c);
}
#else
__device__ __forceinline__ v2f pk_fma(v2f a, v2f b, v2f c) {
    v2f d; d.x = fmaf(a.x, b.x, c.x); d.y = fmaf(a.y, b.y, c.y); return d;
}
#endif

struct GruK2 { v2f rW, rU, rC, zW, zU, zC, nW, nC, nU, nD; };
struct GruKs { float rW, rU, rC, zW, zU, zC, nW, nC, nU, nD; };

__device__ __forceinline__ GruK2 make_k2(
    const float* __restrict__ w_ih, const float* __restrict__ w_hh,
    const float* __restrict__ b_ih, const float* __restrict__ b_hh,
    int la, int lb)
{
    GruK2 K;
    #pragma unroll
    for (int s = 0; s < 2; ++s) {
        const int l = s ? lb : la;
        K.rW[s] = -LOG2E * w_ih[l*3+0]; K.rU[s] = -LOG2E * w_hh[l*3+0];
        K.rC[s] = -LOG2E * (b_ih[l*3+0] + b_hh[l*3+0]);
        K.zW[s] = -LOG2E * w_ih[l*3+1]; K.zU[s] = -LOG2E * w_hh[l*3+1];
        K.zC[s] = -LOG2E * (b_ih[l*3+1] + b_hh[l*3+1]);
        K.nW[s] = -2.0f*LOG2E * w_ih[l*3+2]; K.nC[s] = -2.0f*LOG2E * b_ih[l*3+2];
        K.nU[s] = -2.0f*LOG2E * w_hh[l*3+2]; K.nD[s] = -2.0f*LOG2E * b_hh[l*3+2];
    }
    return K;
}

__device__ __forceinline__ GruKs make_ks(
    const float* __restrict__ w_ih, const float* __restrict__ w_hh,
    const float* __restrict__ b_ih, const float* __restrict__ b_hh, int l)
{
    GruKs K;
    K.rW = -LOG2E * w_ih[l*3+0]; K.rU = -LOG2E * w_hh[l*3+0];
    K.rC = -LOG2E * (b_ih[l*3+0] + b_hh[l*3+0]);
    K.zW = -LOG2E * w_ih[l*3+1]; K.zU = -LOG2E * w_hh[l*3+1];
    K.zC = -LOG2E * (b_ih[l*3+1] + b_hh[l*3+1]);
    K.nW = -2.0f*LOG2E * w_ih[l*3+2]; K.nC = -2.0f*LOG2E * b_ih[l*3+2];
    K.nU = -2.0f*LOG2E * w_hh[l*3+2]; K.nD = -2.0f*LOG2E * b_hh[l*3+2];
    return K;
}

// Fused triple GRU cell with MERGED RECIPROCALS. Same math as rounds 4-14
// (er/ez/en are e^{-a} forms; r = 1/(1+er);
//  h' = (ez*(1-en) + h*(1+en)) / ((1+ez)*(1+en)))
// except the 6 rcps per lane-tick become 2: rcp(abc) + pair-products recover
// each 1/a to ~3ulp. Products bounded by 2^102 (|gate args| <= ~22 bits of
// exponent) — no overflow. Output compare is bf16-granular, so the ~1e-6
// per-step drift is invisible.
__device__ __forceinline__ void tri_cell(
    const GruK2& K01, const GruKs& K2, v2f h01, float h2, float xa,
    v2f& n01, float& n2)
{
    const v2f ONE = (v2f){1.0f, 1.0f};
    v2f in01; in01.x = xa; in01.y = h01.x;
    const float in2 = h01.y;
    // A — gate args
    float ar2 = fmaf(K2.rU, h2, fmaf(K2.rW, in2, K2.rC));
    float az2 = fmaf(K2.zU, h2, fmaf(K2.zW, in2, K2.zC));
    v2f ar01 = pk_fma(K01.rU, h01, pk_fma(K01.rW, in01, K01.rC));
    v2f az01 = pk_fma(K01.zU, h01, pk_fma(K01.zW, in01, K01.zC));
    // B — 6x exp2
    float er2 = fast_exp2(ar2);
    float ez2 = fast_exp2(az2);
    v2f er01; er01.x = fast_exp2(ar01.x); er01.y = fast_exp2(ar01.y);
    v2f ez01; ez01.x = fast_exp2(az01.x); ez01.y = fast_exp2(az01.y);
    // C — 3 r-gates via ONE rcp: 1/a = rcp(abc)*(bc)
    float a = 1.0f + er2, b = 1.0f + er01.x, c = 1.0f + er01.y;
    float ab = a * b, bc = b * c, ac = a * c;
    float ir = fast_rcp(ab * c);
    float r2 = ir * bc;
    v2f r01; r01.x = ir * ac; r01.y = ir * ab;
    // D — n args + 3x exp2
    float an2 = fmaf(r2, fmaf(K2.nU, h2, K2.nD), fmaf(K2.nW, in2, K2.nC));
    v2f an01 = pk_fma(r01, pk_fma(K01.nU, h01, K01.nD), pk_fma(K01.nW, in01, K01.nC));
    float en2 = fast_exp2(an2);
    v2f en01; en01.x = fast_exp2(an01.x); en01.y = fast_exp2(an01.y);
    // E — finals via ONE rcp (h2 path first: its consumer shfl can issue early)
    float num2 = fmaf(en2, h2 - ez2, h2 + ez2);
    v2f num01 = pk_fma(en01, h01 - ez01, h01 + ez01);
    float d = (1.0f + ez2) * (1.0f + en2);
    float e = (1.0f + ez01.x) * (1.0f + en01.x);
    float f = (1.0f + ez01.y) * (1.0f + en01.y);
    float de = d * e, ef = e * f, df = d * f;
    float iq = fast_rcp(de * f);
    n2 = num2 * (ef * iq);
    n01.x = num01.x * (df * iq);
    n01.y = num01.y * (de * iq);
}

// Ring-pipelined GRU: 8-lane rings, 3 CONSECUTIVE layers per lane, ONE chain
// per lane, SW-pipelined ring handoff (r9 structure — best measured; r14's
// wave stagger reverted, proven neutral). Round-15 change: merged-rcp
// tri_cell cuts trans instrs 15 -> 11 per lane-tick (trans-issue-bound per
// the r9/r11 busy-cycle fit: trans ~ 11-13 cyc/instr).
__global__ __launch_bounds__(256, 2) void gru_pipe_kernel(
    const float* __restrict__ inputs, const float* __restrict__ w_ih,
    const float* __restrict__ w_hh, const float* __restrict__ b_ih,
    const float* __restrict__ b_hh, const int* __restrict__ horizon_p,
    float* __restrict__ hv, float* __restrict__ h_out)
{
    __shared__ float xl[32][TLEN + 1];   // 32 chains/block, +1 pad
    const int tid = threadIdx.x;
    const int wid = tid >> 6;
    const int lane = tid & 63;
    const int ring = lane >> 3;          // 0..7
    const int sl = lane & 7;             // ring-local lane
    const int L0 = 3 * sl;               // first owned layer
    const int chain_local = wid * 8 + ring;
    const int c = blockIdx.x * 32 + chain_local;

    const GruK2 K01 = make_k2(w_ih, w_hh, b_ih, b_hh, L0, L0 + 1);
    const GruKs K2  = make_ks(w_ih, w_hh, b_ih, b_hh, L0 + 2);

    for (int i = tid; i < 32 * TLEN; i += 256) {
        const int cl = i / TLEN, t = i - cl * TLEN;
        const int cc = blockIdx.x * 32 + cl;
        const int node = cc >> 4, b = cc & 15;
        xl[cl][t] = inputs[((size_t)b * NODES + node) * TLEN + t];
    }
    __syncthreads();

    const int H = *horizon_p;
    const int last = H * TLEN;                        // 192 for H=8
    const int ringsrc = (lane & 56) | ((sl + 7) & 7); // prev lane in 8-ring
    const bool lead = (sl == 0);
    const float* xrow = &xl[chain_local][0];

    v2f h01 = (v2f){0.0f, 0.0f};
    float h2 = 0.0f;
    float rel = 0.0f;   // == shfl(h2 after tick k-1); h2 init 0 -> rel 0

    // Fill: ticks [0, 24). Lead lane's first slot takes the original input.
    for (int k = 0; k < TLEN; ++k) {
        float inA = lead ? xrow[k] : rel;
        v2f n01; float n2;
        tri_cell(K01, K2, h01, h2, inA, n01, n2);
        h01.x = (k >= L0 + 0) ? n01.x : h01.x;
        h01.y = (k >= L0 + 1) ? n01.y : h01.y;
        h2    = (k >= L0 + 2) ? n2   : h2;
        rel = __shfl(h2, ringsrc, 64);               // for tick k+1
    }
    // Steady: ticks [24, last) — no masks; shfl SW-pipelined (rel consumed
    // one tick after issue).
    #pragma unroll 8
    for (int k = TLEN; k < last; ++k) {
        v2f n01; float n2;
        tri_cell(K01, K2, h01, h2, rel, n01, n2);
        h01 = n01;
        h2 = n2;
        rel = __shfl(h2, ringsrc, 64);
    }
    // Drain: ticks [last, last+23). Layer l's last update is tick l+last-1.
    for (int k = last; k < last + LAYERS - 1; ++k) {
        v2f n01; float n2;
        tri_cell(K01, K2, h01, h2, rel, n01, n2);
        h01.x = (k < L0 + 0 + last) ? n01.x : h01.x;
        h01.y = (k < L0 + 1 + last) ? n01.y : h01.y;
        h2    = (k < L0 + 2 + last) ? n2   : h2;
        rel = __shfl(h2, ringsrc, 64);
    }

    // Outputs: hv[L][c] scratch and h_out[node][L][b].
    const int node = c >> 4, b = c & 15;
    float* ho = h_out + (size_t)node * (LAYERS * BATCH) + b;
    hv[(size_t)(L0 + 0) * NLANES + c] = h01.x;  ho[(L0 + 0) * BATCH] = h01.x;
    hv[(size_t)(L0 + 1) * NLANES + c] = h01.y;  ho[(L0 + 1) * BATCH] = h01.y;
    hv[(size_t)(L0 + 2) * NLANES + c] = h2;     ho[(L0 + 2) * BATCH] = h2;
}

// adj[l][i][j] = dot_b(hv[l,i,:], hv[l,j,:]) * inv_i * inv_j.
// 64x64 tile per 256-thread block; B tile transposed in LDS (conflict-free).
// At the HBM-write floor (~100 MB output at ~6.5 TB/s measured, ~16 us).
__global__ __launch_bounds__(256) void adj_kernel(
    const float* __restrict__ hv, float* __restrict__ adj)
{
    const int l = blockIdx.z;
    const int i0 = blockIdx.y * 64;
    const int j0 = blockIdx.x * 64;
    __shared__ float As[64 * 16];   // [row][k]
    __shared__ float Bt[16 * 64];   // [k][col]
    __shared__ float iA[64];
    __shared__ float iB[64];
    const int tid = threadIdx.x;
    const float* hvl = hv + (size_t)l * NLANES;

    ((float4*)As)[tid] = ((const float4*)(hvl + (size_t)i0 * 16))[tid];
    {
        const int j = tid >> 2;
        const int kc = (tid & 3) * 4;
        float4 bv = *(const float4*)(hvl + (size_t)(j0 + j) * 16 + kc);
        Bt[(kc + 0) * 64 + j] = bv.x;
        Bt[(kc + 1) * 64 + j] = bv.y;
        Bt[(kc + 2) * 64 + j] = bv.z;
        Bt[(kc + 3) * 64 + j] = bv.w;
    }
    __syncthreads();

    if (tid < 64) {
        float s = 0.0f;
        #pragma unroll
        for (int k = 0; k < 16; ++k) { float v = As[tid * 16 + k]; s = fmaf(v, v, s); }
        iA[tid] = fast_rcp(fmaxf(sqrtf(s), 1e-8f));
    } else if (tid < 128) {
        const int j = tid - 64;
        float s = 0.0f;
        #pragma unroll
        for (int k = 0; k < 16; ++k) { float v = Bt[k * 64 + j]; s = fmaf(v, v, s); }
        iB[j] = fast_rcp(fmaxf(sqrtf(s), 1e-8f));
    }
    __syncthreads();

    const int ty = tid >> 4;   // row group (4 rows)
    const int tx = tid & 15;   // col group (4 cols = 1 float4)

    float4 acc0 = {0,0,0,0}, acc1 = {0,0,0,0}, acc2 = {0,0,0,0}, acc3 = {0,0,0,0};
    #pragma unroll
    for (int kk = 0; kk < 4; ++kk) {
        float4 a0 = ((const float4*)As)[(ty * 4 + 0) * 4 + kk];
        float4 a1 = ((const float4*)As)[(ty * 4 + 1) * 4 + kk];
        float4 a2 = ((const float4*)As)[(ty * 4 + 2) * 4 + kk];
        float4 a3 = ((const float4*)As)[(ty * 4 + 3) * 4 + kk];
        #pragma unroll
        for (int e = 0; e < 4; ++e) {
            const int k = kk * 4 + e;
            float4 bk = ((const float4*)Bt)[k * 16 + tx];
            const float a0e = (e == 0) ? a0.x : (e == 1) ? a0.y : (e == 2) ? a0.z : a0.w;
            const float a1e = (e == 0) ? a1.x : (e == 1) ? a1.y : (e == 2) ? a1.z : a1.w;
            const float a2e = (e == 0) ? a2.x : (e == 1) ? a2.y : (e == 2) ? a2.z : a2.w;
            const float a3e = (e == 0) ? a3.x : (e == 1) ? a3.y : (e == 2) ? a3.z : a3.w;
            acc0.x = fmaf(a0e, bk.x, acc0.x); acc0.y = fmaf(a0e, bk.y, acc0.y);
            acc0.z = fmaf(a0e, bk.z, acc0.z); acc0.w = fmaf(a0e, bk.w, acc0.w);
            acc1.x = fmaf(a1e, bk.x, acc1.x); acc1.y = fmaf(a1e, bk.y, acc1.y);
            acc1.z = fmaf(a1e, bk.z, acc1.z); acc1.w = fmaf(a1e, bk.w, acc1.w);
            acc2.x = fmaf(a2e, bk.x, acc2.x); acc2.y = fmaf(a2e, bk.y, acc2.y);
            acc2.z = fmaf(a2e, bk.z, acc2.z); acc2.w = fmaf(a2e, bk.w, acc2.w);
            acc3.x = fmaf(a3e, bk.x, acc3.x); acc3.y = fmaf(a3e, bk.y, acc3.y);
            acc3.z = fmaf(a3e, bk.z, acc3.z); acc3.w = fmaf(a3e, bk.w, acc3.w);
        }
    }

    float* out = adj + (size_t)l * NODES * NODES;
    const float4 ib4 = ((const float4*)iB)[tx];
    #pragma unroll
    for (int ii = 0; ii < 4; ++ii) {
        const int i = i0 + ty * 4 + ii;
        const float si = iA[ty * 4 + ii];
        float4 a = (ii == 0) ? acc0 : (ii == 1) ? acc1 : (ii == 2) ? acc2 : acc3;
        float4 w;
        w.x = a.x * si * ib4.x;
        w.y = a.y * si * ib4.y;
        w.z = a.z * si * ib4.z;
        w.w = a.w * si * ib4.w;
        *(float4*)(out + (size_t)i * NODES + j0 + tx * 4) = w;
    }
}

extern "C" void kernel_launch(void* const* d_in, const int* in_sizes, int n_in,
                              void* d_out, int out_size, void* d_ws, size_t ws_size,
                              hipStream_t stream) {
    const float* inputs = (const float*)d_in[0];
    const float* w_ih   = (const float*)d_in[1];
    const float* w_hh   = (const float*)d_in[2];
    const float* b_ih   = (const float*)d_in[3];
    const float* b_hh   = (const float*)d_in[4];
    const int*   horiz  = (const int*)d_in[5];

    float* adj   = (float*)d_out;                                   // [24,1024,1024]
    float* h_out = (float*)d_out + (size_t)LAYERS * NODES * NODES;  // [1024,24,16]
    float* hv    = (float*)d_ws;                                    // [24][16384]

    // 512 blocks x 256 threads = 2048 waves = 2/SIMD; 32 chains/block
    gru_pipe_kernel<<<NLANES / 32, 256, 0, stream>>>(inputs, w_ih, w_hh, b_ih, b_hh,
                                                     horiz, hv, h_out);

    dim3 grid(NODES / 64, NODES / 64, LAYERS);
    adj_kernel<<<grid, 256, 0, stream>>>(hv, adj);
}